// Round 8
// baseline (24166.353 us; speedup 1.0000x reference)
//
#include <hip/hip_runtime.h>
#include <math.h>

#define B_ 64
#define T_ 512
#define F_ 128
#define H_ 512
#define NBLK 384
#define SPIN_MAX (1 << 23)

typedef short bf16x8 __attribute__((ext_vector_type(8)));
typedef float f32x4 __attribute__((ext_vector_type(4)));
typedef int   i32x4 __attribute__((ext_vector_type(4)));

// ---------------------------------------------------------------------------
// One-time input permute: input[b][t][f] -> xbf[t][b][f] (A-frag friendly:
// each MFMA lane reads 8 consecutive f for its b).
// ---------------------------------------------------------------------------
__global__ void transpose_x(const float* __restrict__ in, float* __restrict__ xbf) {
    const int t = blockIdx.x;
    for (int idx = threadIdx.x; idx < B_ * F_; idx += blockDim.x) {
        const int bb = idx >> 7, f = idx & (F_ - 1);
        xbf[(size_t)t * B_ * F_ + idx] = in[(size_t)bb * T_ * F_ + (size_t)t * F_ + f];
    }
}

__device__ __forceinline__ float sigmoid_(float x) { return 1.0f / (1.0f + expf(-x)); }

// Device-coherent 4B ops (relaxed agent-scope atomics -> sc1 point-to-point
// coherent, no cache-walk fences). All h-buffer traffic uses these.
__device__ __forceinline__ float loadc(const float* p) {
    return __hip_atomic_load(p, __ATOMIC_RELAXED, __HIP_MEMORY_SCOPE_AGENT);
}
__device__ __forceinline__ void storec(float* p, float v) {
    __hip_atomic_store(p, v, __ATOMIC_RELAXED, __HIP_MEMORY_SCOPE_AGENT);
}

// Round-to-nearest bf16 (staging only; one-time cost).
__device__ __forceinline__ unsigned short bf_rn(float f) {
    unsigned u = __float_as_uint(f);
    u += 0x7FFF + ((u >> 16) & 1);
    return (unsigned short)(u >> 16);
}

// Pack 8 fp32 -> hi/lo bf16 A-fragments (truncation split: hi=trunc bf16,
// lo=trunc bf16 of residual; combined rel err ~2^-16, 3 ops/element).
__device__ __forceinline__ void pack_frags(const float f[8], bf16x8& ah, bf16x8& al) {
    union Frag { i32x4 i; bf16x8 s; } H, L;
    float lo[8];
#pragma unroll
    for (int j = 0; j < 8; ++j)
        lo[j] = f[j] - __uint_as_float(__float_as_uint(f[j]) & 0xFFFF0000u);
#pragma unroll
    for (int p = 0; p < 4; ++p) {
        H.i[p] = __builtin_amdgcn_perm(__float_as_uint(f[2 * p + 1]),
                                       __float_as_uint(f[2 * p]), 0x07060302u);
        L.i[p] = __builtin_amdgcn_perm(__float_as_uint(lo[2 * p + 1]),
                                       __float_as_uint(lo[2 * p]), 0x07060302u);
    }
    ah = H.s; al = L.s;
}

// ---------------------------------------------------------------------------
// Fence-free grid barrier with bounded spins. vmcnt drain first (h stores
// reach the coherence point), arrive-store to own slot, block 0 aggregates
// in parallel and broadcasts `go`. Monotone epochs.
// ---------------------------------------------------------------------------
__device__ __forceinline__ void gbar(int* __restrict__ slots, int* __restrict__ go,
                                     int bid, int tid, int e) {
    asm volatile("s_waitcnt vmcnt(0) lgkmcnt(0)" ::: "memory");
    __syncthreads();
    if (tid == 0)
        __hip_atomic_store(&slots[bid * 16], e, __ATOMIC_RELAXED,
                           __HIP_MEMORY_SCOPE_AGENT);
    if (bid == 0) {
        for (int s2 = tid; s2 < NBLK; s2 += 256) {
            int guard = 0;
            while (__hip_atomic_load(&slots[s2 * 16], __ATOMIC_RELAXED,
                                     __HIP_MEMORY_SCOPE_AGENT) < e &&
                   ++guard < SPIN_MAX)
                __builtin_amdgcn_s_sleep(1);
        }
        __syncthreads();
        if (tid == 0)
            __hip_atomic_store(go, e, __ATOMIC_RELAXED, __HIP_MEMORY_SCOPE_AGENT);
    } else if (tid == 0) {
        int guard = 0;
        while (__hip_atomic_load(go, __ATOMIC_RELAXED,
                                 __HIP_MEMORY_SCOPE_AGENT) < e &&
               ++guard < SPIN_MAX)
            __builtin_amdgcn_s_sleep(1);
    }
    __syncthreads();
}

// ---------------------------------------------------------------------------
// One step's GEMM for this wave via MFMA: D[16 b][16 rows] over unified
// K = [x-seg | h-seg]. B-frags (weights, split bf16) from LDS pre-swizzled
// fragment order (per-lane distinct 16B, conflict-free). A-frags built from
// fp32 stream ([b][k] layout, 8 contiguous per lane), 6-kstep pipelined.
// 3 MFMAs per kstep: hh + lh + hl (2-term split precision).
// ---------------------------------------------------------------------------
template <int NKX, bool XCOH>
__device__ __forceinline__ void step_mfma(const float* __restrict__ xs_lane,
                                          const float* __restrict__ hs_lane,
                                          const unsigned short* wfrag,
                                          const int lane, f32x4& acc) {
    constexpr int NK = NKX + 16;      // total ksteps (K/32)
    float v[6][8];

    auto load8 = [&](float* dst, int i) {
        const float* p = (i < NKX) ? (xs_lane + i * 32)
                                   : (hs_lane + (i - NKX) * 32);
        const bool coh = (i < NKX) ? XCOH : true;
#pragma unroll
        for (int j = 0; j < 8; ++j) dst[j] = coh ? loadc(p + j) : p[j];
    };

#pragma unroll
    for (int p = 0; p < 6; ++p) load8(v[p], p);

#pragma unroll
    for (int i = 0; i < NK; ++i) {
        bf16x8 ah, al;
        pack_frags(v[i % 6], ah, al);          // consume buffer
        if (i + 6 < NK) load8(v[i % 6], i + 6); // refill for kstep i+6
        union Frag { i32x4 i4; bf16x8 s; } BH, BL;
        BH.i4 = *(const i32x4*)&wfrag[i * 1024 + lane * 8];
        BL.i4 = *(const i32x4*)&wfrag[i * 1024 + 512 + lane * 8];
        acc = __builtin_amdgcn_mfma_f32_16x16x32_bf16(ah, BH.s, acc, 0, 0, 0);
        acc = __builtin_amdgcn_mfma_f32_16x16x32_bf16(al, BH.s, acc, 0, 0, 0);
        acc = __builtin_amdgcn_mfma_f32_16x16x32_bf16(ah, BL.s, acc, 0, 0, 0);
    }
}

// ---------------------------------------------------------------------------
// Persistent layer-pipelined LSTM scan, MFMA edition.
// Block (layer = bid>>7, cb = bid&127) owns 16 gate-rows (4 cols x 4 gates).
// Wave w = M-tile b in [16w,16w+16), full K. h layout: [parity][b][col].
// LDS: weight frags (split bf16, frag-order) 40/64 KB + D-bounce 4.3 KB
// -> 2 blocks/CU.
// ---------------------------------------------------------------------------
__global__ void __launch_bounds__(256, 2) lstm_scan(
    const float* __restrict__ xbf, float* __restrict__ hb, float* __restrict__ h2T,
    float* __restrict__ h1s, float* __restrict__ out,
    int* __restrict__ bar_slots, int* __restrict__ bar_go,
    const float* __restrict__ Wih0, const float* __restrict__ Whh0,
    const float* __restrict__ bih0, const float* __restrict__ bhh0,
    const float* __restrict__ Wih1, const float* __restrict__ Whh1,
    const float* __restrict__ bih1, const float* __restrict__ bhh1,
    const float* __restrict__ Wih2, const float* __restrict__ Whh2,
    const float* __restrict__ bih2, const float* __restrict__ bhh2,
    const float* __restrict__ fcW1, const float* __restrict__ fcb1,
    const float* __restrict__ fcW2, const float* __restrict__ fcb2) {
    __shared__ unsigned short wfrag[32 * 1024];   // [kstep][hi512|lo512] 64 KB max
    __shared__ float bounce[4][16 * 17];          // per-wave D tiles, padded

    const float* WihA[3] = {Wih0, Wih1, Wih2};
    const float* WhhA[3] = {Whh0, Whh1, Whh2};
    const float* bihA[3] = {bih0, bih1, bih2};
    const float* bhhA[3] = {bhh0, bhh1, bhh2};

    const int tid   = threadIdx.x;
    const int bid   = blockIdx.x;
    const int layer = bid >> 7;
    const int cb    = bid & 127;
    const int c0    = cb * 4;
    const int lane  = tid & 63;
    const int w     = __builtin_amdgcn_readfirstlane(tid >> 6);
    const int lm    = lane & 15;            // MFMA m within tile
    const int lk    = lane >> 4;            // k-octet selector
    const int mb    = w * 16 + lm;          // this lane's batch row (A m-index)
    const int KX    = (layer == 0) ? F_ : H_;
    const int NK    = KX / 32 + 16;
    const int RLX   = (layer == 0) ? F_ : H_;   // x-seg row length

    const float* wih = WihA[layer];
    const float* whh = WhhA[layer];

    // ---- Stage weights once: split bf16 (RN both terms), B-frag order.
    // Frag entry (kstep i, lane l, j): n=l&15 -> (c4=n>>2, g=n&3),
    // k = i*32 + (l>>4)*8 + j, source row g*512+c0+c4 of [Wih|Whh].
    for (int idx = tid; idx < NK * 512; idx += 256) {
        const int i = idx >> 9, rem = idx & 511;
        const int l = rem >> 3, j = rem & 7;
        const int n = l & 15, c4 = n >> 2, g = n & 3;
        const int grow = g * 512 + c0 + c4;
        const int k = i * 32 + (l >> 4) * 8 + j;
        const float f = (k < KX) ? wih[(size_t)grow * KX + k]
                                 : whh[(size_t)grow * 512 + (k - KX)];
        const unsigned short hi = bf_rn(f);
        const float lof = f - __uint_as_float((unsigned)hi << 16);
        wfrag[i * 1024 + l * 8 + j]       = hi;
        wfrag[i * 1024 + 512 + l * 8 + j] = bf_rn(lof);
    }
    __syncthreads();

    // Finalize-role constants: thread owns (col = c0 + (tid>>6), b = tid&63).
    const int fb = tid & 63, fj = tid >> 6;
    const int mycol = c0 + fj;
    float bias[4];
#pragma unroll
    for (int g = 0; g < 4; ++g)
        bias[g] = bihA[layer][g * 512 + mycol] + bhhA[layer][g * 512 + mycol];

    float* hb_l = hb + (size_t)layer * 2 * B_ * H_;     // [parity][b][col]
    const float* hb_in = hb + (size_t)(layer - 1) * 2 * B_ * H_;

    float c_reg = 0.0f;

    for (int s = 0; s < T_ + 2; ++s) {
        const int t = s - layer;
        if (t >= 0 && t < T_) {
            const int p_out  = t & 1;
            const int p_prev = (t + 1) & 1;
            const float* xs_lane =
                ((layer == 0) ? (xbf + (size_t)t * B_ * F_)
                              : (hb_in + (size_t)p_out * B_ * H_)) +
                (size_t)mb * RLX + lk * 8;
            const float* hs_lane =
                hb_l + (size_t)p_prev * B_ * H_ + (size_t)mb * H_ + lk * 8;

            f32x4 acc = {0.f, 0.f, 0.f, 0.f};
            if (layer == 0) step_mfma<4, false>(xs_lane, hs_lane, wfrag, lane, acc);
            else            step_mfma<16, true>(xs_lane, hs_lane, wfrag, lane, acc);

            // D -> bounce: lane holds n=lane&15, m=(lane>>4)*4+r (b within tile)
#pragma unroll
            for (int r = 0; r < 4; ++r)
                bounce[w][(lane & 15) * 17 + (lane >> 4) * 4 + r] = acc[r];
            __syncthreads();

            // finalize: gates for (col=mycol, b=fb) live at n=fj*4+g, tile fb>>4
            float a[4];
#pragma unroll
            for (int g = 0; g < 4; ++g)
                a[g] = bias[g] + bounce[fb >> 4][(fj * 4 + g) * 17 + (fb & 15)];

            const float ig = sigmoid_(a[0]);
            const float fg = sigmoid_(a[1]);
            const float gg = tanhf(a[2]);
            const float og = sigmoid_(a[3]);
            c_reg = fg * c_reg + ig * gg;
            const float hv = og * tanhf(c_reg);
            storec(&hb_l[(size_t)p_out * B_ * H_ + (size_t)fb * H_ + mycol], hv);
            if (layer == 2 && t == T_ - 1)
                storec(&h2T[(size_t)mycol * B_ + fb], hv);   // [k][b] for FC head
        }
        gbar(bar_slots, bar_go, bid, tid, s + 1);
    }

    // ---- FC head: h1 = relu(fcW1 @ h2 + b1); out = relu(fcW2 @ h1 + b2)
    float* redsc = &bounce[0][0];
    if (bid < 64) {
        float part = 0.0f;
        const float* wrow = fcW1 + (size_t)bid * H_ + w * 128;
        const float* hseg = h2T + (size_t)(w * 128) * B_ + fb;
#pragma unroll 8
        for (int k = 0; k < 128; ++k)
            part = fmaf(wrow[k], loadc(hseg + (size_t)k * B_), part);
        redsc[w * 64 + fb] = part;
        __syncthreads();
        if (tid < 64) {
            float acc2 = fcb1[bid] + redsc[tid] + redsc[64 + tid] +
                         redsc[128 + tid] + redsc[192 + tid];
            storec(&h1s[bid * B_ + tid], fmaxf(acc2, 0.0f));
        }
    }
    gbar(bar_slots, bar_go, bid, tid, T_ + 3);
    if (bid == 0 && tid < 64) {
        float acc2 = fcb2[0];
#pragma unroll
        for (int c = 0; c < 64; ++c)
            acc2 = fmaf(fcW2[c], loadc(&h1s[c * B_ + tid]), acc2);
        out[tid] = fmaxf(acc2, 0.0f);
    }
}

// ---------------------------------------------------------------------------
extern "C" void kernel_launch(void* const* d_in, const int* in_sizes, int n_in,
                              void* d_out, int out_size, void* d_ws, size_t ws_size,
                              hipStream_t stream) {
    const float* in    = (const float*)d_in[0];
    const float* Wih0  = (const float*)d_in[1];
    const float* Whh0  = (const float*)d_in[2];
    const float* bih0  = (const float*)d_in[3];
    const float* bhh0  = (const float*)d_in[4];
    const float* Wih1  = (const float*)d_in[5];
    const float* Whh1  = (const float*)d_in[6];
    const float* bih1  = (const float*)d_in[7];
    const float* bhh1  = (const float*)d_in[8];
    const float* Wih2  = (const float*)d_in[9];
    const float* Whh2  = (const float*)d_in[10];
    const float* bih2  = (const float*)d_in[11];
    const float* bhh2  = (const float*)d_in[12];
    const float* fcW1  = (const float*)d_in[13];
    const float* fcb1  = (const float*)d_in[14];
    const float* fcW2  = (const float*)d_in[15];
    const float* fcb2  = (const float*)d_in[16];
    float* outp = (float*)d_out;

    float* ws  = (float*)d_ws;
    float* xbf = ws;                                   // [T][B][F]   16 MB
    float* hbf = xbf + (size_t)T_ * B_ * F_;           // [3][2][B][H] 768 KB
    float* h2T = hbf + (size_t)3 * 2 * B_ * H_;        // [H][B]      128 KB
    float* h1s = h2T + (size_t)H_ * B_;                // [64][64]     16 KB
    int*   bar = (int*)(h1s + 64 * 64);
    int*   bar_slots = bar;                            // NBLK*16 ints
    int*   bar_go    = bar + NBLK * 16;                // 1 int

    hipMemsetAsync(hbf, 0,
                   ((size_t)3 * 2 * B_ * H_ + (size_t)H_ * B_ + 64 * 64 +
                    NBLK * 16 + 16) * sizeof(float),
                   stream);

    transpose_x<<<dim3(T_), dim3(256), 0, stream>>>(in, xbf);

    void* args[] = {
        (void*)&xbf, (void*)&hbf, (void*)&h2T, (void*)&h1s, (void*)&outp,
        (void*)&bar_slots, (void*)&bar_go,
        (void*)&Wih0, (void*)&Whh0, (void*)&bih0, (void*)&bhh0,
        (void*)&Wih1, (void*)&Whh1, (void*)&bih1, (void*)&bhh1,
        (void*)&Wih2, (void*)&Whh2, (void*)&bih2, (void*)&bhh2,
        (void*)&fcW1, (void*)&fcb1, (void*)&fcW2, (void*)&fcb2};
    hipLaunchCooperativeKernel((void*)lstm_scan, dim3(NBLK), dim3(256), args, 0, stream);
}

// Round 9
// 4893.814 us; speedup vs baseline: 4.9381x; 4.9381x over previous
//
#include <hip/hip_runtime.h>
#include <math.h>

#define B_ 64
#define T_ 512
#define F_ 128
#define H_ 512
#define NBLK 384
#define SPIN_MAX (1 << 23)

typedef short bf16x8 __attribute__((ext_vector_type(8)));
typedef float f32x4 __attribute__((ext_vector_type(4)));
typedef int   i32x4 __attribute__((ext_vector_type(4)));

// ---------------------------------------------------------------------------
// One-time input transpose: input[b][t][f] -> xT[t][f][b]  (B-operand layout)
// ---------------------------------------------------------------------------
__global__ void transpose_x(const float* __restrict__ in, float* __restrict__ xT) {
    __shared__ float tile[F_][B_ + 1];
    const int t   = blockIdx.x;
    const int tid = threadIdx.x;
    for (int idx = tid; idx < B_ * F_; idx += blockDim.x) {
        int bb = idx >> 7, f = idx & (F_ - 1);
        tile[f][bb] = in[(size_t)bb * T_ * F_ + (size_t)t * F_ + f];
    }
    __syncthreads();
    for (int idx = tid; idx < B_ * F_; idx += blockDim.x) {
        int f = idx >> 6, bb = idx & (B_ - 1);
        xT[(size_t)t * F_ * B_ + (size_t)f * B_ + bb] = tile[f][bb];
    }
}

__device__ __forceinline__ float sigmoid_(float x) { return 1.0f / (1.0f + expf(-x)); }

// Device-coherent 4B ops (relaxed agent-scope atomics -> sc1 point-to-point
// coherent, no cache-walk fences). All h-buffer traffic uses these.
__device__ __forceinline__ float loadc(const float* p) {
    return __hip_atomic_load(p, __ATOMIC_RELAXED, __HIP_MEMORY_SCOPE_AGENT);
}
__device__ __forceinline__ void storec(float* p, float v) {
    __hip_atomic_store(p, v, __ATOMIC_RELAXED, __HIP_MEMORY_SCOPE_AGENT);
}

// Round-to-nearest bf16 (staging only).
__device__ __forceinline__ unsigned short bf_rn(float f) {
    unsigned u = __float_as_uint(f);
    u += 0x7FFF + ((u >> 16) & 1);
    return (unsigned short)(u >> 16);
}

// Pack 8 fp32 -> hi/lo bf16 fragments (truncation split; hi+lo rel err ~2^-16).
__device__ __forceinline__ void pack_frags(const float f[8], bf16x8& bh, bf16x8& bl) {
    union Frag { i32x4 i; bf16x8 s; } Hh, Ll;
    float lo[8];
#pragma unroll
    for (int j = 0; j < 8; ++j)
        lo[j] = f[j] - __uint_as_float(__float_as_uint(f[j]) & 0xFFFF0000u);
#pragma unroll
    for (int p = 0; p < 4; ++p) {
        Hh.i[p] = __builtin_amdgcn_perm(__float_as_uint(f[2 * p + 1]),
                                        __float_as_uint(f[2 * p]), 0x07060302u);
        Ll.i[p] = __builtin_amdgcn_perm(__float_as_uint(lo[2 * p + 1]),
                                        __float_as_uint(lo[2 * p]), 0x07060302u);
    }
    bh = Hh.s; bl = Ll.s;
}

// ---------------------------------------------------------------------------
// Fence-free grid barrier with bounded spins (proven R6/R7).
// ---------------------------------------------------------------------------
__device__ __forceinline__ void gbar(int* __restrict__ slots, int* __restrict__ go,
                                     int bid, int tid, int e) {
    asm volatile("s_waitcnt vmcnt(0) lgkmcnt(0)" ::: "memory");
    __syncthreads();
    if (tid == 0)
        __hip_atomic_store(&slots[bid * 16], e, __ATOMIC_RELAXED,
                           __HIP_MEMORY_SCOPE_AGENT);
    if (bid == 0) {
        for (int s2 = tid; s2 < NBLK; s2 += 256) {
            int guard = 0;
            while (__hip_atomic_load(&slots[s2 * 16], __ATOMIC_RELAXED,
                                     __HIP_MEMORY_SCOPE_AGENT) < e &&
                   ++guard < SPIN_MAX)
                __builtin_amdgcn_s_sleep(1);
        }
        __syncthreads();
        if (tid == 0)
            __hip_atomic_store(go, e, __ATOMIC_RELAXED, __HIP_MEMORY_SCOPE_AGENT);
    } else if (tid == 0) {
        int guard = 0;
        while (__hip_atomic_load(go, __ATOMIC_RELAXED,
                                 __HIP_MEMORY_SCOPE_AGENT) < e &&
               ++guard < SPIN_MAX)
            __builtin_amdgcn_s_sleep(1);
    }
    __syncthreads();
}

// ---------------------------------------------------------------------------
// One step's GEMM for this wave: D[16 gate-rows][16 b] over K = [x-seg|h-seg].
// A = weights (split bf16) from LDS in frag order (lane*16 b128 reads,
// m97-verified conflict-free). B = fp32 stream in [k][b] layout: lane n=b ->
// per-instruction 64B-coalesced quarter-groups; packed to split bf16 in VALU.
// 3 independent MFMA chains (hh, lh, hl) -> no serial acc dependency.
// sp0 = stream base already offset by this lane's (b + k-octet).
// ---------------------------------------------------------------------------
template <int NKX, bool XCOH>
__device__ __forceinline__ void step_mfma(const float* __restrict__ xs_l,
                                          const float* __restrict__ hs_l,
                                          const unsigned short* wfrag,
                                          const int lane, f32x4 acc[3]) {
    constexpr int NK = NKX + 16;      // total ksteps (K/32)
    float v[6][8];

    auto load8 = [&](float* dst, int i) {
        const float* p = (i < NKX) ? (xs_l + (size_t)(i * 32) * 64)
                                   : (hs_l + (size_t)((i - NKX) * 32) * 64);
        const bool coh = (i < NKX) ? XCOH : true;
#pragma unroll
        for (int j = 0; j < 8; ++j) dst[j] = coh ? loadc(p + j * 64) : p[j * 64];
    };

#pragma unroll
    for (int p = 0; p < 6; ++p) load8(v[p], p);

#pragma unroll
    for (int i = 0; i < NK; ++i) {
        bf16x8 bh, bl;
        pack_frags(v[i % 6], bh, bl);
        if (i + 6 < NK) load8(v[i % 6], i + 6);
        union Frag { i32x4 i4; bf16x8 s; } AH, AL;
        AH.i4 = *(const i32x4*)&wfrag[i * 1024 + lane * 8];
        AL.i4 = *(const i32x4*)&wfrag[i * 1024 + 512 + lane * 8];
        acc[0] = __builtin_amdgcn_mfma_f32_16x16x32_bf16(AH.s, bh, acc[0], 0, 0, 0);
        acc[1] = __builtin_amdgcn_mfma_f32_16x16x32_bf16(AL.s, bh, acc[1], 0, 0, 0);
        acc[2] = __builtin_amdgcn_mfma_f32_16x16x32_bf16(AH.s, bl, acc[2], 0, 0, 0);
    }
}

// ---------------------------------------------------------------------------
// Persistent layer-pipelined LSTM scan, MFMA + in-register finalize.
// Block (layer=bid>>7, cb=bid&127) owns 16 gate-rows m=4*c4+g (cols c0..c0+3,
// gates i,f,g,o). Wave w owns b-tile [16w,16w+16). Lane (n=lane&15, q=lane>>4)
// finalizes (b=16w+n, col=c0+q): its 4 D-regs are exactly that pair's 4 gates.
// h layout [layer][parity][col][b] -> coalesced stores, B-operand-ready reads.
// ---------------------------------------------------------------------------
__global__ void __launch_bounds__(256, 2) lstm_scan(
    const float* __restrict__ xT, float* __restrict__ hb,
    float* __restrict__ h1s, float* __restrict__ out,
    int* __restrict__ bar_slots, int* __restrict__ bar_go,
    const float* __restrict__ Wih0, const float* __restrict__ Whh0,
    const float* __restrict__ bih0, const float* __restrict__ bhh0,
    const float* __restrict__ Wih1, const float* __restrict__ Whh1,
    const float* __restrict__ bih1, const float* __restrict__ bhh1,
    const float* __restrict__ Wih2, const float* __restrict__ Whh2,
    const float* __restrict__ bih2, const float* __restrict__ bhh2,
    const float* __restrict__ fcW1, const float* __restrict__ fcb1,
    const float* __restrict__ fcW2, const float* __restrict__ fcb2) {
    __shared__ unsigned short wfrag[32 * 1024];   // [kstep][hi512|lo512], <=64 KB
    __shared__ float redsc[4 * 64];               // FC-head reduction only

    const float* WihA[3] = {Wih0, Wih1, Wih2};
    const float* WhhA[3] = {Whh0, Whh1, Whh2};
    const float* bihA[3] = {bih0, bih1, bih2};
    const float* bhhA[3] = {bhh0, bhh1, bhh2};

    const int tid   = threadIdx.x;
    const int bid   = blockIdx.x;
    const int layer = bid >> 7;
    const int cb    = bid & 127;
    const int c0    = cb * 4;
    const int lane  = tid & 63;
    const int w     = __builtin_amdgcn_readfirstlane(tid >> 6);
    const int KX    = (layer == 0) ? F_ : H_;
    const int NK    = KX / 32 + 16;

    const float* wih = WihA[layer];
    const float* whh = WhhA[layer];

    // ---- Stage weights once: split bf16 (RN both terms), A-frag order.
    // Entry (kstep i, frag-lane l, j): m=l&15 -> row grow=(m&3)*512+c0+(m>>2),
    // k = i*32 + (l>>4)*8 + j over [Wih row | Whh row].
    for (int idx = tid; idx < NK * 512; idx += 256) {
        const int i = idx >> 9, rem = idx & 511;
        const int l = rem >> 3, j = rem & 7;
        const int m = l & 15;
        const int grow = (m & 3) * 512 + c0 + (m >> 2);
        const int k = i * 32 + (l >> 4) * 8 + j;
        const float f = (k < KX) ? wih[(size_t)grow * KX + k]
                                 : whh[(size_t)grow * 512 + (k - KX)];
        const unsigned short hi = bf_rn(f);
        const float lof = f - __uint_as_float((unsigned)hi << 16);
        wfrag[i * 1024 + l * 8 + j]       = hi;
        wfrag[i * 1024 + 512 + l * 8 + j] = bf_rn(lof);
    }
    __syncthreads();

    // Finalize-role constants: lane owns (b = 16w + n, col = c0 + q).
    const int fb    = w * 16 + (lane & 15);
    const int mycol = c0 + (lane >> 4);
    float bias[4];
#pragma unroll
    for (int g = 0; g < 4; ++g)
        bias[g] = bihA[layer][g * 512 + mycol] + bhhA[layer][g * 512 + mycol];

    float* hb_l = hb + (size_t)layer * 2 * H_ * B_;        // [parity][col][b]
    const float* hb_in = hb + (size_t)(layer - 1) * 2 * H_ * B_;

    float c_reg = 0.0f;
    const int boff = w * 16 + (lane & 15) + ((lane >> 4) * 8) * 64; // b + koctet*64

    for (int s = 0; s < T_ + 2; ++s) {
        const int t = s - layer;
        if (t >= 0 && t < T_) {
            const int p_out  = t & 1;
            const int p_prev = (t + 1) & 1;
            const float* xs_l =
                ((layer == 0) ? (xT + (size_t)t * F_ * B_)
                              : (hb_in + (size_t)p_out * H_ * B_)) + boff;
            const float* hs_l = hb_l + (size_t)p_prev * H_ * B_ + boff;

            f32x4 acc[3] = {{0.f,0.f,0.f,0.f},{0.f,0.f,0.f,0.f},{0.f,0.f,0.f,0.f}};
            if (layer == 0) step_mfma<4, false>(xs_l, hs_l, wfrag, lane, acc);
            else            step_mfma<16, true>(xs_l, hs_l, wfrag, lane, acc);

            // In-register finalize: reg r = gate r of (fb, mycol).
            float a[4];
#pragma unroll
            for (int g = 0; g < 4; ++g)
                a[g] = bias[g] + acc[0][g] + acc[1][g] + acc[2][g];

            const float ig = sigmoid_(a[0]);
            const float fg = sigmoid_(a[1]);
            const float gg = tanhf(a[2]);
            const float og = sigmoid_(a[3]);
            c_reg = fg * c_reg + ig * gg;
            const float hv = og * tanhf(c_reg);
            storec(&hb_l[(size_t)p_out * H_ * B_ + (size_t)mycol * B_ + fb], hv);
        }
        gbar(bar_slots, bar_go, bid, tid, s + 1);
    }

    // ---- FC head. h2 = layer-2 h at t=511 (parity 1), layout [col][b].
    const float* h2 = hb + (size_t)(2 * 2 + 1) * H_ * B_;
    const int fcb = tid & 63;
    if (bid < 64) {
        float part = 0.0f;
        const float* wrow = fcW1 + (size_t)bid * H_ + w * 128;
        const float* hseg = h2 + (size_t)(w * 128) * B_ + fcb;
#pragma unroll 8
        for (int k = 0; k < 128; ++k)
            part = fmaf(wrow[k], loadc(hseg + (size_t)k * B_), part);
        redsc[w * 64 + fcb] = part;
        __syncthreads();
        if (tid < 64) {
            float acc2 = fcb1[bid] + redsc[tid] + redsc[64 + tid] +
                         redsc[128 + tid] + redsc[192 + tid];
            storec(&h1s[bid * B_ + tid], fmaxf(acc2, 0.0f));
        }
    }
    gbar(bar_slots, bar_go, bid, tid, T_ + 3);
    if (bid == 0 && tid < 64) {
        float acc2 = fcb2[0];
#pragma unroll
        for (int c = 0; c < 64; ++c)
            acc2 = fmaf(fcW2[c], loadc(&h1s[c * B_ + tid]), acc2);
        out[tid] = fmaxf(acc2, 0.0f);
    }
}

// ---------------------------------------------------------------------------
extern "C" void kernel_launch(void* const* d_in, const int* in_sizes, int n_in,
                              void* d_out, int out_size, void* d_ws, size_t ws_size,
                              hipStream_t stream) {
    const float* in    = (const float*)d_in[0];
    const float* Wih0  = (const float*)d_in[1];
    const float* Whh0  = (const float*)d_in[2];
    const float* bih0  = (const float*)d_in[3];
    const float* bhh0  = (const float*)d_in[4];
    const float* Wih1  = (const float*)d_in[5];
    const float* Whh1  = (const float*)d_in[6];
    const float* bih1  = (const float*)d_in[7];
    const float* bhh1  = (const float*)d_in[8];
    const float* Wih2  = (const float*)d_in[9];
    const float* Whh2  = (const float*)d_in[10];
    const float* bih2  = (const float*)d_in[11];
    const float* bhh2  = (const float*)d_in[12];
    const float* fcW1  = (const float*)d_in[13];
    const float* fcb1  = (const float*)d_in[14];
    const float* fcW2  = (const float*)d_in[15];
    const float* fcb2  = (const float*)d_in[16];
    float* outp = (float*)d_out;

    float* ws  = (float*)d_ws;
    float* xT  = ws;                                   // [T][F][B]     16 MB
    float* hbf = xT + (size_t)T_ * F_ * B_;            // [3][2][H][B] 768 KB
    float* h1s = hbf + (size_t)3 * 2 * H_ * B_;        // [64][64]      16 KB
    int*   bar = (int*)(h1s + 64 * 64);
    int*   bar_slots = bar;                            // NBLK*16 ints
    int*   bar_go    = bar + NBLK * 16;                // 1 int

    hipMemsetAsync(hbf, 0,
                   ((size_t)3 * 2 * H_ * B_ + 64 * 64 + NBLK * 16 + 16) * sizeof(float),
                   stream);

    transpose_x<<<dim3(T_), dim3(256), 0, stream>>>(in, xT);

    void* args[] = {
        (void*)&xT, (void*)&hbf, (void*)&h1s, (void*)&outp,
        (void*)&bar_slots, (void*)&bar_go,
        (void*)&Wih0, (void*)&Whh0, (void*)&bih0, (void*)&bhh0,
        (void*)&Wih1, (void*)&Whh1, (void*)&bih1, (void*)&bhh1,
        (void*)&Wih2, (void*)&Whh2, (void*)&bih2, (void*)&bhh2,
        (void*)&fcW1, (void*)&fcb1, (void*)&fcW2, (void*)&fcb2};
    hipLaunchCooperativeKernel((void*)lstm_scan, dim3(NBLK), dim3(256), args, 0, stream);
}